// Round 9
// baseline (329.160 us; speedup 1.0000x reference)
//
#include <hip/hip_runtime.h>
#include <cstdint>
#include <cstddef>

#define E 1024
#define TT 2048
#define NB 2
#define NH 16
#define HD 64

using u16 = unsigned short;
using bf16x8 = __attribute__((ext_vector_type(8))) __bf16;
using floatx4 = __attribute__((ext_vector_type(4))) float;
using s16x4 = __attribute__((ext_vector_type(4))) short;

__device__ __forceinline__ float b2f(u16 u) {
  unsigned int x = ((unsigned int)u) << 16;
  float f;
  __builtin_memcpy(&f, &x, 4);
  return f;
}
__device__ __forceinline__ u16 f2b(float f) {
  unsigned int x;
  __builtin_memcpy(&x, &f, 4);
  x += 0x7fffu + ((x >> 16) & 1u);
  return (u16)(x >> 16);
}
__device__ __forceinline__ u16 f2b_fast(float f) {  // compensated truncation
  unsigned int x;
  float g = f * 1.001953125f;
  __builtin_memcpy(&x, &g, 4);
  return (u16)(x >> 16);
}

__device__ __forceinline__ void async16(const u16* g, u16* l) {
  __builtin_amdgcn_global_load_lds(
      (const __attribute__((address_space(1))) unsigned int*)g,
      (__attribute__((address_space(3))) unsigned int*)l, 16, 0, 0);
}

__device__ __forceinline__ floatx4 mfma32(bf16x8 a, bf16x8 b, floatx4 c) {
  return __builtin_amdgcn_mfma_f32_16x16x32_bf16(a, b, c, 0, 0, 0);
}

// v_mfma_f32_16x16x16_bf16 (A/B = 4 bf16 in 2 VGPRs). Builtin only exists on
// the device target; host pass parses this body too, so guard it.
__device__ __forceinline__ floatx4 mfma16(s16x4 a, s16x4 b, floatx4 c) {
#if defined(__HIP_DEVICE_COMPILE__)
  return __builtin_amdgcn_mfma_f32_16x16x16bf16_1k(a, b, c, 0, 0, 0);
#else
  return c;
#endif
}

// ---------------- merged weight convert fp32[K][N] -> bf16[N][K] ----------------
__global__ __launch_bounds__(256) void wconv_all(
    const float* __restrict__ w0, const float* __restrict__ w1,
    const float* __restrict__ w2, const float* __restrict__ w3,
    u16* __restrict__ o0, u16* __restrict__ o1, u16* __restrict__ o2,
    u16* __restrict__ o3) {
  __shared__ float tile[32][33];
  const int t = blockIdx.x;
  const float* w;
  u16* o;
  int K, N, nx, ti;
  if (t < 3072) { w = w0; o = o0; K = 1024; N = 3072; nx = 96; ti = t; }
  else if (t < 4096) { w = w1; o = o1; K = 1024; N = 1024; nx = 32; ti = t - 3072; }
  else if (t < 8192) { w = w2; o = o2; K = 1024; N = 4096; nx = 128; ti = t - 4096; }
  else { w = w3; o = o3; K = 4096; N = 1024; nx = 32; ti = t - 8192; }
  const int n0 = (ti % nx) * 32, k0 = (ti / nx) * 32;
  const int tx = threadIdx.x, ty = threadIdx.y;
#pragma unroll
  for (int i = 0; i < 32; i += 8)
    tile[ty + i][tx] = w[(size_t)(k0 + ty + i) * N + (n0 + tx)];
  __syncthreads();
#pragma unroll
  for (int i = 0; i < 32; i += 8)
    o[(size_t)(n0 + ty + i) * K + (k0 + tx)] = f2b(tile[tx][ty + i]);
}

// ---------------- LayerNorm fp32 in -> bf16 out ----------------
__global__ __launch_bounds__(256) void ln_kernel(const float* __restrict__ x,
                                                 const float* __restrict__ w,
                                                 const float* __restrict__ bvec,
                                                 u16* __restrict__ outb) {
  const int row = blockIdx.x;
  const int t = threadIdx.x;
  const float4 v = ((const float4*)(x + (size_t)row * E))[t];
  float s1 = v.x + v.y + v.z + v.w;
  float s2 = v.x * v.x + v.y * v.y + v.z * v.z + v.w * v.w;
#pragma unroll
  for (int off = 32; off > 0; off >>= 1) {
    s1 += __shfl_down(s1, off);
    s2 += __shfl_down(s2, off);
  }
  __shared__ float r1[4], r2[4];
  if ((t & 63) == 0) { r1[t >> 6] = s1; r2[t >> 6] = s2; }
  __syncthreads();
  s1 = r1[0] + r1[1] + r1[2] + r1[3];
  s2 = r2[0] + r2[1] + r2[2] + r2[3];
  const float mean = s1 * (1.f / E);
  const float var = s2 * (1.f / E) - mean * mean;
  const float rstd = rsqrtf(var + 1e-5f);
  const float4 wv = ((const float4*)w)[t];
  const float4 bv = ((const float4*)bvec)[t];
  const u16 o0 = f2b((v.x - mean) * rstd * wv.x + bv.x);
  const u16 o1 = f2b((v.y - mean) * rstd * wv.y + bv.y);
  const u16 o2 = f2b((v.z - mean) * rstd * wv.z + bv.z);
  const u16 o3 = f2b((v.w - mean) * rstd * wv.w + bv.w);
  uint2 pk;
  pk.x = (unsigned)o0 | ((unsigned)o1 << 16);
  pk.y = (unsigned)o2 | ((unsigned)o3 << 16);
  ((uint2*)(outb + (size_t)row * E))[t] = pk;
}

// ---------------- GEMM (fat): C[M][N] = A[M][K](bf16) * BT[N][K](bf16)^T --------
// 256x256 tile (was 256x128): halves staged fabric bytes per FLOP and cuts
// LDS-reads per MFMA (12 reads : 32 MFMA/wave/K-step vs 12:16). 512 threads,
// 8 waves as 2M x 4N, wave tile 128x64, acc 8x4 floatx4.
// Proven 2-phase pipeline form: DEPTH=3 buffers (96KB LDS), ONE barrier/iter,
// counted non-draining vmcnt(4) (4 loads/stage, 1 stage in flight beyond
// current). Grid: fc (16,16)=256 blocks = 1/CU exact; qkv (12,16)=192.
// MODE 2: out bf16 = gelu(acc + bias)
// MODE 3: qkv split: col<1024 -> qb row-major; col<2048 -> kb row-major;
//         col>=2048 -> vtb transposed [n][4096] bf16 (packed 4-row stores)
template <int MODE>
__global__ __launch_bounds__(512) void gemm_bt(const u16* __restrict__ A,
                                               const u16* __restrict__ BT,
                                               const float* __restrict__ bias,
                                               const float* __restrict__ res,
                                               void* __restrict__ outp,
                                               int M, int N, int K) {
  __shared__ __align__(16) u16 As[3][256 * 32];  // 48 KB
  __shared__ __align__(16) u16 Bs[3][256 * 32];  // 48 KB
  const int tid = threadIdx.x;
  const int wave = tid >> 6, lane = tid & 63;

  // XCD-aware rasterization (dispatch round-robins blocks over 8 XCDs).
  // Bijective for gx in {12,16}, gy=16 (cpg=gx/4, rpg=8).
  const int gx = gridDim.x, gy = gridDim.y;
  const int L = blockIdx.y * gx + blockIdx.x;
  const int xc = L & 7, wi = L >> 3;
  const int cpg = gx >> 2;
  const int rpg = gy >> 1;
  const int bxs = (xc >> 1) * cpg + (wi % cpg);
  const int bys = (xc & 1) * rpg + (wi / cpg);

  const int row0 = bys * 256, col0 = bxs * 256;
  const int wm = (wave & 1) * 128;        // 2 M-waves x 128 rows
  const int wn = (wave >> 1) * 64;        // 4 N-waves x 64 cols
  const int r = lane & 15, qd = lane >> 4;

  floatx4 acc[8][4];
#pragma unroll
  for (int i = 0; i < 8; i++)
#pragma unroll
    for (int j = 0; j < 4; j++) acc[i][j] = (floatx4){0.f, 0.f, 0.f, 0.f};

  // staging: 1024 16B-chunks per matrix per stage (row = c>>2, slot = c&3)
  const u16* ApA = A + (size_t)(row0 + (tid >> 2)) * K + (tid & 3) * 8;
  const u16* ApB = A + (size_t)(row0 + 128 + (tid >> 2)) * K + (tid & 3) * 8;
  const u16* BpA = BT + (size_t)(col0 + (tid >> 2)) * K + (tid & 3) * 8;
  const u16* BpB = BT + (size_t)(col0 + 128 + (tid >> 2)) * K + (tid & 3) * 8;

  auto stage = [&](int kt, u16* Asb, u16* Bsb) {
    async16(ApA + kt, Asb + tid * 8);
    async16(ApB + kt, Asb + (512 + tid) * 8);
    async16(BpA + kt, Bsb + tid * 8);
    async16(BpB + kt, Bsb + (512 + tid) * 8);
  };
  auto compute = [&](const u16* Asb, const u16* Bsb) {
    bf16x8 af[8], bfr[4];
#pragma unroll
    for (int i = 0; i < 8; i++)
      af[i] = *(const bf16x8*)&Asb[(wm + i * 16 + r) * 32 + qd * 8];
#pragma unroll
    for (int j = 0; j < 4; j++)
      bfr[j] = *(const bf16x8*)&Bsb[(wn + j * 16 + r) * 32 + qd * 8];
#pragma unroll
    for (int i = 0; i < 8; i++)
#pragma unroll
      for (int j = 0; j < 4; j++)
        acc[i][j] = mfma32(af[i], bfr[j], acc[i][j]);
  };

  const int nIter = K >> 5;
  stage(0, As[0], Bs[0]);
  stage(32, As[1], Bs[1]);
  for (int tt = 0; tt < nIter; tt += 3) {
#pragma unroll
    for (int d = 0; d < 3; d++) {
      const int t = tt + d;
      if (t >= nIter) break;  // uniform across block
      if (t + 1 < nIter)
        asm volatile("s_waitcnt vmcnt(4)" ::: "memory");  // stage(t) complete
      else
        asm volatile("s_waitcnt vmcnt(0)" ::: "memory");
      asm volatile("s_barrier" ::: "memory");
      if (t + 2 < nIter) {
        const int sd = (d + 2 >= 3) ? d - 1 : d + 2;  // (d+2)%3, static
        stage((t + 2) * 32, As[sd], Bs[sd]);
      }
      compute(As[d], Bs[d]);
    }
  }

#pragma unroll
  for (int i = 0; i < 8; i++) {
#pragma unroll
    for (int j = 0; j < 4; j++) {
      const int col = col0 + wn + j * 16 + r;
      const float bc = bias[col];
      if (MODE == 3) {
        u16* base = (u16*)outp;
        const int rowb = row0 + wm + i * 16 + qd * 4;
        if (col < 2048) {
          const size_t cb =
              (col < 1024) ? (size_t)col : ((size_t)4096 * 1024 + (col - 1024));
#pragma unroll
          for (int rr = 0; rr < 4; rr++)
            base[cb + (size_t)(rowb + rr) * 1024] = f2b(acc[i][j][rr] + bc);
        } else {
          ushort4 pk;
          pk.x = f2b(acc[i][j][0] + bc);
          pk.y = f2b(acc[i][j][1] + bc);
          pk.z = f2b(acc[i][j][2] + bc);
          pk.w = f2b(acc[i][j][3] + bc);
          *(ushort4*)(base + (size_t)8 * 1024 * 1024 +
                      (size_t)(col - 2048) * 4096 + rowb) = pk;
        }
      } else {
#pragma unroll
        for (int rr = 0; rr < 4; rr++) {
          const int row = row0 + wm + i * 16 + qd * 4 + rr;
          const float v = acc[i][j][rr] + bc;
          const size_t idx = (size_t)row * N + col;
          if (MODE == 0) {
            ((u16*)outp)[idx] = f2b(v);
          } else if (MODE == 1) {
            ((float*)outp)[idx] = v + res[idx];
          } else {
            const float z = 1.5957691216f * v * (1.f + 0.044715f * v * v);
            const float g = v / (1.f + __expf(-z));
            ((u16*)outp)[idx] = f2b(g);
          }
        }
      }
    }
  }
}

// ------------- GEMM (skinny, split-K in block): out f32 = A*BT^T + bias + res ----
// R3-proven version (~55 us on proj, cross-run noise +-3%). 128x128 tile,
// grid 256 blocks. 8 waves as 2M x 2N x 2K: wave tile 64x64; pair-reduce via
// LDS scratch. 4-deep 32KB stages (128KB LDS), static buffer indices, single
// barrier/iter, counted non-draining vmcnt. Requires K % 256 == 0.
// (R6's global split-K + atomicAdd REGRESSED: atomic WRITE traffic cost more
// than the occupancy gain. R1's deeper prefetch also regressed. Plateau.)
__global__ __launch_bounds__(512) void gemm_ks(const u16* __restrict__ A,
                                               const u16* __restrict__ BT,
                                               const float* __restrict__ bias,
                                               const float* __restrict__ res,
                                               float* __restrict__ outp,
                                               int M, int N, int K) {
  __shared__ __align__(16) u16 As[4][2][128 * 32];  // 64 KB
  __shared__ __align__(16) u16 Bs[4][2][128 * 32];  // 64 KB
  const int tid = threadIdx.x;
  const int wave = tid >> 6, lane = tid & 63;

  const int gx = gridDim.x, gy = gridDim.y;
  const int L = blockIdx.y * gx + blockIdx.x;
  const int xc = L & 7, wi = L >> 3;
  const int cpg = gx >> 2, rpg = gy >> 1;
  const int bxs = (xc >> 1) * cpg + (wi % cpg);
  const int bys = (xc & 1) * rpg + (wi / cpg);

  const int row0 = bys * 128, col0 = bxs * 128;
  const int kg = wave >> 2;                 // k-group: 0 = even chunks, 1 = odd
  const int wm = (wave & 1) * 64, wn = ((wave >> 1) & 1) * 64;
  const int r = lane & 15, qd = lane >> 4;

  floatx4 acc[4][4];
#pragma unroll
  for (int i = 0; i < 4; i++)
#pragma unroll
    for (int j = 0; j < 4; j++) acc[i][j] = (floatx4){0.f, 0.f, 0.f, 0.f};

  // per-thread staging: row = tid>>2, 16B slot = tid&3 (covers a 128x32 chunk)
  const int arow = tid >> 2, aslot = (tid & 3) * 8;
  const u16* Ap = A + (size_t)(row0 + arow) * K + aslot;
  const u16* Bp = BT + (size_t)(col0 + arow) * K + aslot;

  auto stage = [&](int s, int d) {   // stage s covers k = s*64 .. s*64+63
    const int k0 = s * 64;
    async16(Ap + k0, &As[d][0][tid * 8]);
    async16(Ap + k0 + 32, &As[d][1][tid * 8]);
    async16(Bp + k0, &Bs[d][0][tid * 8]);
    async16(Bp + k0 + 32, &Bs[d][1][tid * 8]);
  };
  auto compute = [&](int d) {
    bf16x8 af[4], bfr[4];
#pragma unroll
    for (int i = 0; i < 4; i++)
      af[i] = *(const bf16x8*)&As[d][kg][(wm + i * 16 + r) * 32 + qd * 8];
#pragma unroll
    for (int j = 0; j < 4; j++)
      bfr[j] = *(const bf16x8*)&Bs[d][kg][(wn + j * 16 + r) * 32 + qd * 8];
#pragma unroll
    for (int i = 0; i < 4; i++)
#pragma unroll
      for (int j = 0; j < 4; j++)
        acc[i][j] = mfma32(af[i], bfr[j], acc[i][j]);
  };

  const int nT = K >> 6;  // chunk-pairs; multiple of 4 for K in {1024, 4096}
  stage(0, 0);
  stage(1, 1);
  stage(2, 2);
  for (int tt = 0; tt < nT; tt += 4) {
#pragma unroll
    for (int d = 0; d < 4; d++) {
      const int t = tt + d;
      const int rem = nT - 1 - t;  // stages outstanding beyond t
      if (rem >= 2)
        asm volatile("s_waitcnt vmcnt(8)" ::: "memory");  // stage(t) complete
      else if (rem == 1)
        asm volatile("s_waitcnt vmcnt(4)" ::: "memory");
      else
        asm volatile("s_waitcnt vmcnt(0)" ::: "memory");
      asm volatile("s_barrier" ::: "memory");
      if (t + 3 < nT) stage(t + 3, (d + 3) & 3);
      compute(d);
    }
  }

  // ---- pair reduction (w, w+4) via LDS scratch (reuse As: 64 KB) ----
  __syncthreads();
  float* S = (float*)&As[0][0][0];
  const int p = wave & 3;
  floatx4* W = (floatx4*)S + p * 1024 + lane;
  if (kg == 1) {
#pragma unroll
    for (int i = 0; i < 4; i++)
#pragma unroll
      for (int j = 0; j < 4; j++) W[(i * 4 + j) * 64] = acc[i][j];
  }
  __syncthreads();
  if (kg == 0) {
#pragma unroll
    for (int i = 0; i < 4; i++) {
#pragma unroll
      for (int j = 0; j < 4; j++) {
        const floatx4 w2 = W[(i * 4 + j) * 64];
        const int col = col0 + wn + j * 16 + r;
        const float bc = bias[col];
#pragma unroll
        for (int rr = 0; rr < 4; rr++) {
          const int row = row0 + wm + i * 16 + qd * 4 + rr;
          const size_t idx = (size_t)row * N + col;
          outp[idx] = acc[i][j][rr] + w2[rr] + bc + res[idx];
        }
      }
    }
  }
}

// ---------------- MFMA causal flash attention, register-resident P ----------------
// 8 waves x 512 threads: wq = wave&3 picks the 32-q sub-tile (2 fragments),
// kvh = wave>>2 picks which half of the 8 ks-chunks this wave computes.
// kv-split halves per-wave work -> 2 waves/SIMD even in the long tail.
// Partial O/lsum pair-reduced once via LDS scratch at the end, then the
// R0-proven shfl normalize chain.
// Load balance: co-resident pair (L, L+256) differs only in blockIdx.z;
// qt = b ? 15-bx : bx gives every CU exactly 17 kv-iterations.
__global__ __launch_bounds__(512, 4) void attn_mfma(const u16* __restrict__ qb,
                                                    const u16* __restrict__ kb,
                                                    const u16* __restrict__ vtb,
                                                    u16* __restrict__ y) {
  const int bx = blockIdx.x;                                  // 16 q-tiles
  const int h = blockIdx.y, b = blockIdx.z;
  const int qt = b ? (15 - bx) : bx;                          // CU-complementary
  const int tid = threadIdx.x;
  const int wave = tid >> 6, lane = tid & 63;
  const int quad = lane >> 4, r = lane & 15;
  const int wq = wave & 3;    // q sub-tile (32 rows)
  const int kvh = wave >> 2;  // ks half: chunks [kvh*4, kvh*4+4)

  __shared__ __align__(16) u16 lds[2 * 128 * 64 + 2 * 64 * 128];  // 64 KB
  u16* KsB = lds;                  // [2][128*64] [key][d], d-chunks XOR-swizzled
  u16* VsB = lds + 2 * 128 * 64;   // [2][64*128] [d][key], key-chunks XOR-swizzled

  const float C = 0.125f * 1.44269504f;  // softmax scale folded into exp2, into Q
  const int qbase = qt * 128 + wq * 32;

  // Q fragments as B-operand (n=q=lane&15, k=d=quad*8+j), pre-scaled by C
  bf16x8 qf[2][2];
#pragma unroll
  for (int f = 0; f < 2; f++) {
    const u16* qp = qb + ((size_t)b * TT + qbase + f * 16 + r) * E + h * 64;
#pragma unroll
    for (int kh = 0; kh < 2; kh++) {
      union { bf16x8 v; u16 u[8]; } tmp;
#pragma unroll
      for (int j = 0; j < 8; j++) tmp.u[j] = f2b(b2f(qp[kh * 32 + quad * 8 + j]) * C);
      qf[f][kh] = tmp.v;
    }
  }

  floatx4 o[2][4];
#pragma unroll
  for (int f = 0; f < 2; f++)
#pragma unroll
    for (int i = 0; i < 4; i++) o[f][i] = (floatx4){0.f, 0.f, 0.f, 0.f};
  float lsum[2] = {0.f, 0.f};
  const bool mgt[4] = {(quad * 4 + 0) > r, (quad * 4 + 1) > r,
                       (quad * 4 + 2) > r, (quad * 4 + 3) > r};

  auto stageKV = [&](int it, int bi) {
    const int k0 = it * 128;
    u16* Kd = KsB + bi * (128 * 64);
    u16* Vd = VsB + bi * (64 * 128);
#pragma unroll
    for (int i = 0; i < 2; i++) {
      const int c = tid + i * 512;
      const int key = c >> 3, dc = (c & 7) ^ (key & 7);
      async16(kb + ((size_t)b * TT + k0 + key) * E + h * 64 + dc * 8, Kd + c * 8);
    }
#pragma unroll
    for (int i = 0; i < 2; i++) {
      const int c = tid + i * 512;
      const int d = c >> 4, kc = (c & 15) ^ (d & 15);
      async16(vtb + (size_t)(h * 64 + d) * (NB * TT) + b * TT + k0 + kc * 8,
              Vd + c * 8);
    }
  };

  const int nIter = qt + 1;
  stageKV(0, 0);
  for (int it = 0; it < nIter; it++) {
    if (it + 1 < nIter) {
      stageKV(it + 1, (it + 1) & 1);
      asm volatile("s_waitcnt vmcnt(4)" ::: "memory");
    } else {
      asm volatile("s_waitcnt vmcnt(0)" ::: "memory");
    }
    asm volatile("s_barrier" ::: "memory");
    const u16* Kb = KsB + (it & 1) * (128 * 64);
    const u16* Vb = VsB + (it & 1) * (64 * 128);
    const int k0 = it * 128;
    const int relA = (qbase - k0) >> 4;  // frag-0 straddle chunk (>=8 on full tiles)
    const int kTop = (relA + 1 < 7) ? (relA + 1) : 7;

#pragma unroll
    for (int kk = 0; kk < 4; kk++) {
      const int ks = kvh * 4 + kk;
      if (ks <= kTop) {
        // ---- S^T = K Q^T for this 16-key chunk, both q-fragments ----
        const int key = ks * 16 + r, kx = key & 7;
        const bf16x8 kf0 = *(const bf16x8*)&Kb[key * 64 + (quad ^ kx) * 8];
        const bf16x8 kf1 = *(const bf16x8*)&Kb[key * 64 + ((4 + quad) ^ kx) * 8];
        floatx4 s0 = (floatx4){0.f, 0.f, 0.f, 0.f};
        s0 = mfma32(kf0, qf[0][0], s0);
        s0 = mfma32(kf1, qf[0][1], s0);
        floatx4 s1 = (floatx4){0.f, 0.f, 0.f, 0.f};
        s1 = mfma32(kf0, qf[1][0], s1);
        s1 = mfma32(kf1, qf[1][1], s1);

        // ---- V fragments for this chunk ----
        s16x4 vf[4];
#pragma unroll
        for (int dsub = 0; dsub < 4; dsub++) {
          const int d = dsub * 16 + r;
          vf[dsub] = *(const s16x4*)&Vb[d * 128 + ((2 * ks + (quad >> 1)) ^ r) * 8 +
                                        (quad & 1) * 4];
        }

        // ---- P = exp2(S); O += P V; lsum += P ----
#pragma unroll
        for (int f = 0; f < 2; f++) {
          const floatx4 sv = (f == 0) ? s0 : s1;
          const int rel = relA + f;
          if (ks <= rel) {
            float p0 = exp2f(sv[0]);
            float p1 = exp2f(sv[1]);
            float p2 = exp2f(sv[2]);
            float p3 = exp2f(sv[3]);
            if (ks == rel) {  // diagonal straddle: lane-constant causal mask
              if (mgt[0]) p0 = 0.f;
              if (mgt[1]) p1 = 0.f;
              if (mgt[2]) p2 = 0.f;
              if (mgt[3]) p3 = 0.f;
            }
            lsum[f] += p0 + p1 + p2 + p3;
            s16x4 pk;
            pk[0] = (short)f2b_fast(p0);
            pk[1] = (short)f2b_fast(p1);
            pk[2] = (short)f2b_fast(p2);
            pk[3] = (short)f2b_fast(p3);
#pragma unroll
            for (int dsub = 0; dsub < 4; dsub++)
              o[f][dsub] = mfma16(pk, vf[dsub], o[f][dsub]);
          }
        }
      }
    }
    asm volatile("s_barrier" ::: "memory");
  }

  // ---- epilogue: pair (wq: kvh=0/1) reduction via LDS scratch, then the
  // R0-proven shfl normalize chain (lv@lane = rowsum for q = r per wave).
  floatx4* W = (floatx4*)(float*)lds + wq * 576 + lane;  // 9 slots/pair, 36 KB
  if (kvh == 1) {
#pragma unroll
    for (int f = 0; f < 2; f++)
#pragma unroll
      for (int dsub = 0; dsub < 4; dsub++) W[(f * 4 + dsub) * 64] = o[f][dsub];
    W[8 * 64] = (floatx4){lsum[0], lsum[1], 0.f, 0.f};
  }
  __syncthreads();
  if (kvh == 0) {
    const floatx4 ls2 = W[8 * 64];
#pragma unroll
    for (int f = 0; f < 2; f++) {
      float lv = lsum[f] + ((f == 0) ? ls2[0] : ls2[1]);
      lv += __shfl_xor(lv, 16);
      lv += __shfl_xor(lv, 32);  // lv@lane = total row-sum for q = qbase+f*16+(lane&15)
      float linv[4];
#pragma unroll
      for (int rr = 0; rr < 4; rr++) linv[rr] = 1.f / __shfl(lv, quad * 4 + rr);
#pragma unroll
      for (int dsub = 0; dsub < 4; dsub++) {
        const floatx4 o2 = W[(f * 4 + dsub) * 64];
#pragma unroll
        for (int rr = 0; rr < 4; rr++) {
          const size_t row = (size_t)b * TT + qbase + f * 16 + quad * 4 + rr;
          y[row * E + h * 64 + dsub * 16 + r] =
              f2b((o[f][dsub][rr] + o2[rr]) * linv[rr]);
        }
      }
    }
  }
}

extern "C" void kernel_launch(void* const* d_in, const int* in_sizes, int n_in,
                              void* d_out, int out_size, void* d_ws, size_t ws_size,
                              hipStream_t stream) {
  (void)in_sizes; (void)n_in; (void)out_size; (void)ws_size;
  const float* x      = (const float*)d_in[0];
  const float* ln1w   = (const float*)d_in[1];
  const float* ln1b   = (const float*)d_in[2];
  const float* w_qkv  = (const float*)d_in[3];
  const float* b_qkv  = (const float*)d_in[4];
  const float* w_o    = (const float*)d_in[5];
  const float* b_o    = (const float*)d_in[6];
  const float* ln2w   = (const float*)d_in[7];
  const float* ln2b   = (const float*)d_in[8];
  const float* w_fc   = (const float*)d_in[9];
  const float* b_fc   = (const float*)d_in[10];
  const float* w_proj = (const float*)d_in[11];
  const float* b_proj = (const float*)d_in[12];
  float* out = (float*)d_out;

  char* p = (char*)d_ws;
  u16* wT_qkv  = (u16*)p; p += (size_t)3072 * 1024 * 2;
  u16* wT_o    = (u16*)p; p += (size_t)1024 * 1024 * 2;
  u16* wT_fc   = (u16*)p; p += (size_t)4096 * 1024 * 2;
  u16* wT_proj = (u16*)p; p += (size_t)1024 * 4096 * 2;
  u16* hbuf    = (u16*)p; p += (size_t)4096 * 1024 * 2;   // h -> y -> h2 (serial reuse)
  u16* qkvb    = (u16*)p; p += (size_t)4096 * 3072 * 2;   // qb | kb | vtb
  float* x2    = (float*)p; p += (size_t)4096 * 1024 * 4;
  u16* gbuf    = (u16*)p; p += (size_t)4096 * 4096 * 2;

  u16* qb  = qkvb;
  u16* kb  = qkvb + (size_t)4096 * 1024;
  u16* vtb = qkvb + (size_t)8 * 1024 * 1024;

  // all four weight transposes in one launch
  wconv_all<<<12288, dim3(32, 8), 0, stream>>>(w_qkv, w_o, w_fc, w_proj,
                                               wT_qkv, wT_o, wT_fc, wT_proj);

  // h = LN1(x)
  ln_kernel<<<4096, 256, 0, stream>>>(x, ln1w, ln1b, hbuf);
  // qkv = h @ w_qkv + b_qkv  (split: qb, kb row-major; vtb transposed)
  gemm_bt<3><<<dim3(3072 / 256, 4096 / 256), 512, 0, stream>>>(
      hbuf, wT_qkv, b_qkv, nullptr, qkvb, 4096, 3072, 1024);
  // y = attention(q,k,v)   (writes into hbuf, h is dead)
  attn_mfma<<<dim3(16, NH, NB), 512, 0, stream>>>(qb, kb, vtb, hbuf);
  // x2 = x + y @ w_o + b_o   (split-K skinny GEMM)
  gemm_ks<<<dim3(1024 / 128, 4096 / 128), 512, 0, stream>>>(
      hbuf, wT_o, b_o, x, x2, 4096, 1024, 1024);
  // h2 = LN2(x2)  (into hbuf, y is dead)
  ln_kernel<<<4096, 256, 0, stream>>>(x2, ln2w, ln2b, hbuf);
  // g = gelu(h2 @ w_fc + b_fc)
  gemm_bt<2><<<dim3(4096 / 256, 4096 / 256), 512, 0, stream>>>(
      hbuf, wT_fc, b_fc, nullptr, gbuf, 4096, 4096, 1024);
  // out = x2 + g @ w_proj + b_proj   (split-K skinny GEMM)
  gemm_ks<<<dim3(1024 / 128, 4096 / 128), 512, 0, stream>>>(
      gbuf, wT_proj, b_proj, x2, out, 4096, 1024, 4096);
}

// Round 10
// 322.227 us; speedup vs baseline: 1.0215x; 1.0215x over previous
//
#include <hip/hip_runtime.h>
#include <cstdint>
#include <cstddef>

#define E 1024
#define TT 2048
#define NB 2
#define NH 16
#define HD 64

using u16 = unsigned short;
using bf16x8 = __attribute__((ext_vector_type(8))) __bf16;
using floatx4 = __attribute__((ext_vector_type(4))) float;
using s16x4 = __attribute__((ext_vector_type(4))) short;

__device__ __forceinline__ float b2f(u16 u) {
  unsigned int x = ((unsigned int)u) << 16;
  float f;
  __builtin_memcpy(&f, &x, 4);
  return f;
}
__device__ __forceinline__ u16 f2b(float f) {
  unsigned int x;
  __builtin_memcpy(&x, &f, 4);
  x += 0x7fffu + ((x >> 16) & 1u);
  return (u16)(x >> 16);
}
__device__ __forceinline__ u16 f2b_fast(float f) {  // compensated truncation
  unsigned int x;
  float g = f * 1.001953125f;
  __builtin_memcpy(&x, &g, 4);
  return (u16)(x >> 16);
}

__device__ __forceinline__ void async16(const u16* g, u16* l) {
  __builtin_amdgcn_global_load_lds(
      (const __attribute__((address_space(1))) unsigned int*)g,
      (__attribute__((address_space(3))) unsigned int*)l, 16, 0, 0);
}

__device__ __forceinline__ floatx4 mfma32(bf16x8 a, bf16x8 b, floatx4 c) {
  return __builtin_amdgcn_mfma_f32_16x16x32_bf16(a, b, c, 0, 0, 0);
}

// v_mfma_f32_16x16x16_bf16 (A/B = 4 bf16 in 2 VGPRs). Builtin only exists on
// the device target; host pass parses this body too, so guard it.
__device__ __forceinline__ floatx4 mfma16(s16x4 a, s16x4 b, floatx4 c) {
#if defined(__HIP_DEVICE_COMPILE__)
  return __builtin_amdgcn_mfma_f32_16x16x16bf16_1k(a, b, c, 0, 0, 0);
#else
  return c;
#endif
}

// ---------------- merged weight convert fp32[K][N] -> bf16[N][K] ----------------
// Stores vectorized: one ushort4 (8B) per thread instead of 16 scalar u16
// stores (G13 applies to stores too). LDS read tile[ch*4+j][nl]: bank =
// (4ch+nl+j)%32 -> worst 2-way (free, m136).
__global__ __launch_bounds__(256) void wconv_all(
    const float* __restrict__ w0, const float* __restrict__ w1,
    const float* __restrict__ w2, const float* __restrict__ w3,
    u16* __restrict__ o0, u16* __restrict__ o1, u16* __restrict__ o2,
    u16* __restrict__ o3) {
  __shared__ float tile[32][33];
  const int t = blockIdx.x;
  const float* w;
  u16* o;
  int K, N, nx, ti;
  if (t < 3072) { w = w0; o = o0; K = 1024; N = 3072; nx = 96; ti = t; }
  else if (t < 4096) { w = w1; o = o1; K = 1024; N = 1024; nx = 32; ti = t - 3072; }
  else if (t < 8192) { w = w2; o = o2; K = 1024; N = 4096; nx = 128; ti = t - 4096; }
  else { w = w3; o = o3; K = 4096; N = 1024; nx = 32; ti = t - 8192; }
  const int n0 = (ti % nx) * 32, k0 = (ti / nx) * 32;
  const int tx = threadIdx.x, ty = threadIdx.y;
#pragma unroll
  for (int i = 0; i < 32; i += 8)
    tile[ty + i][tx] = w[(size_t)(k0 + ty + i) * N + (n0 + tx)];
  __syncthreads();
  const int ft = ty * 32 + tx;          // 0..255
  const int nl = ft >> 3, ch = ft & 7;  // out row (n), 4-wide k-chunk
  ushort4 pk;
  pk.x = f2b(tile[ch * 4 + 0][nl]);
  pk.y = f2b(tile[ch * 4 + 1][nl]);
  pk.z = f2b(tile[ch * 4 + 2][nl]);
  pk.w = f2b(tile[ch * 4 + 3][nl]);
  *(ushort4*)(o + (size_t)(n0 + nl) * K + k0 + ch * 4) = pk;
}

// ---------------- LayerNorm fp32 in -> bf16 out ----------------
__global__ __launch_bounds__(256) void ln_kernel(const float* __restrict__ x,
                                                 const float* __restrict__ w,
                                                 const float* __restrict__ bvec,
                                                 u16* __restrict__ outb) {
  const int row = blockIdx.x;
  const int t = threadIdx.x;
  const float4 v = ((const float4*)(x + (size_t)row * E))[t];
  float s1 = v.x + v.y + v.z + v.w;
  float s2 = v.x * v.x + v.y * v.y + v.z * v.z + v.w * v.w;
#pragma unroll
  for (int off = 32; off > 0; off >>= 1) {
    s1 += __shfl_down(s1, off);
    s2 += __shfl_down(s2, off);
  }
  __shared__ float r1[4], r2[4];
  if ((t & 63) == 0) { r1[t >> 6] = s1; r2[t >> 6] = s2; }
  __syncthreads();
  s1 = r1[0] + r1[1] + r1[2] + r1[3];
  s2 = r2[0] + r2[1] + r2[2] + r2[3];
  const float mean = s1 * (1.f / E);
  const float var = s2 * (1.f / E) - mean * mean;
  const float rstd = rsqrtf(var + 1e-5f);
  const float4 wv = ((const float4*)w)[t];
  const float4 bv = ((const float4*)bvec)[t];
  const u16 o0 = f2b((v.x - mean) * rstd * wv.x + bv.x);
  const u16 o1 = f2b((v.y - mean) * rstd * wv.y + bv.y);
  const u16 o2 = f2b((v.z - mean) * rstd * wv.z + bv.z);
  const u16 o3 = f2b((v.w - mean) * rstd * wv.w + bv.w);
  uint2 pk;
  pk.x = (unsigned)o0 | ((unsigned)o1 << 16);
  pk.y = (unsigned)o2 | ((unsigned)o3 << 16);
  ((uint2*)(outb + (size_t)row * E))[t] = pk;
}

// ---------------- GEMM (fat): C[M][N] = A[M][K](bf16) * BT[N][K](bf16)^T --------
// R7-proven version (best measured total 317.1 us): 512 threads, 256x128 tile,
// wave 64x64, DEPTH=3 buffers (72KB LDS -> 2 blocks/CU), ONE barrier/iter,
// counted non-draining vmcnt(3). (R8's 256x256 tile REGRESSED +12us: 1 block/CU
// loses inter-block latency hiding; big tiles need the 8-phase schedule.)
template <int MODE, int ROWS>
__global__ __launch_bounds__(512) void gemm_bt(const u16* __restrict__ A,
                                               const u16* __restrict__ BT,
                                               const float* __restrict__ bias,
                                               const float* __restrict__ res,
                                               void* __restrict__ outp,
                                               int M, int N, int K) {
  constexpr int NJ = (ROWS == 256) ? 4 : 2;
  __shared__ __align__(16) u16 As[3][ROWS * 32];
  __shared__ __align__(16) u16 Bs[3][128 * 32];
  const int tid = threadIdx.x;
  const int wave = tid >> 6, lane = tid & 63;

  // XCD-aware rasterization (dispatch round-robins blocks over 8 XCDs).
  const int gx = gridDim.x, gy = gridDim.y;
  const int L = blockIdx.y * gx + blockIdx.x;
  const int xc = L & 7, wi = L >> 3;
  const int cpg = gx >> 2;
  const int rpg = gy >> 1;
  const int bxs = (xc >> 1) * cpg + (wi % cpg);
  const int bys = (xc & 1) * rpg + (wi / cpg);

  const int row0 = bys * ROWS, col0 = bxs * 128;
  const int wm = (ROWS == 256) ? (wave & 3) * 64 : (wave & 1) * 64;
  const int wn = (ROWS == 256) ? (wave >> 2) * 64 : (wave >> 1) * 32;
  const int r = lane & 15, qd = lane >> 4;

  floatx4 acc[4][NJ];
#pragma unroll
  for (int i = 0; i < 4; i++)
#pragma unroll
    for (int j = 0; j < NJ; j++) acc[i][j] = (floatx4){0.f, 0.f, 0.f, 0.f};

  // staging chunk assignments (16 B chunks; A: ROWS*4 chunks, B: 512 chunks)
  const int cA0 = tid, cA1 = tid + 512, cB = tid;
  const u16* ApA = A + (size_t)(row0 + (cA0 >> 2)) * K + (cA0 & 3) * 8;
  const u16* ApB = A + (size_t)(row0 + (cA1 >> 2)) * K + (cA1 & 3) * 8;
  const u16* Bp = BT + (size_t)(col0 + (cB >> 2)) * K + (cB & 3) * 8;

  auto stage = [&](int kt, u16* Asb, u16* Bsb) {
    async16(ApA + kt, Asb + cA0 * 8);
    if (ROWS == 256) async16(ApB + kt, Asb + cA1 * 8);
    async16(Bp + kt, Bsb + cB * 8);
  };
  auto compute = [&](const u16* Asb, const u16* Bsb) {
    bf16x8 af[4], bfr[NJ];
#pragma unroll
    for (int i = 0; i < 4; i++)
      af[i] = *(const bf16x8*)&Asb[(wm + i * 16 + r) * 32 + qd * 8];
#pragma unroll
    for (int j = 0; j < NJ; j++)
      bfr[j] = *(const bf16x8*)&Bsb[(wn + j * 16 + r) * 32 + qd * 8];
#pragma unroll
    for (int i = 0; i < 4; i++)
#pragma unroll
      for (int j = 0; j < NJ; j++)
        acc[i][j] = mfma32(af[i], bfr[j], acc[i][j]);
  };

  const int nIter = K >> 5;
  stage(0, As[0], Bs[0]);
  stage(32, As[1], Bs[1]);
  for (int tt = 0; tt < nIter; tt += 3) {
#pragma unroll
    for (int d = 0; d < 3; d++) {
      const int t = tt + d;
      if (t >= nIter) break;  // uniform across block
      if (t + 1 < nIter) {
        if (ROWS == 256)
          asm volatile("s_waitcnt vmcnt(3)" ::: "memory");  // stage(t) complete
        else
          asm volatile("s_waitcnt vmcnt(2)" ::: "memory");
      } else {
        asm volatile("s_waitcnt vmcnt(0)" ::: "memory");
      }
      asm volatile("s_barrier" ::: "memory");
      if (t + 2 < nIter) {
        const int sd = (d + 2 >= 3) ? d - 1 : d + 2;  // (d+2)%3, static
        stage((t + 2) * 32, As[sd], Bs[sd]);
      }
      compute(As[d], Bs[d]);
    }
  }

#pragma unroll
  for (int i = 0; i < 4; i++) {
#pragma unroll
    for (int j = 0; j < NJ; j++) {
      const int col = col0 + wn + j * 16 + r;
      const float bc = bias[col];
      if (MODE == 3) {
        u16* base = (u16*)outp;
        const int rowb = row0 + wm + i * 16 + qd * 4;
        if (col < 2048) {
          const size_t cb =
              (col < 1024) ? (size_t)col : ((size_t)4096 * 1024 + (col - 1024));
#pragma unroll
          for (int rr = 0; rr < 4; rr++)
            base[cb + (size_t)(rowb + rr) * 1024] = f2b(acc[i][j][rr] + bc);
        } else {
          ushort4 pk;
          pk.x = f2b(acc[i][j][0] + bc);
          pk.y = f2b(acc[i][j][1] + bc);
          pk.z = f2b(acc[i][j][2] + bc);
          pk.w = f2b(acc[i][j][3] + bc);
          *(ushort4*)(base + (size_t)8 * 1024 * 1024 +
                      (size_t)(col - 2048) * 4096 + rowb) = pk;
        }
      } else {
#pragma unroll
        for (int rr = 0; rr < 4; rr++) {
          const int row = row0 + wm + i * 16 + qd * 4 + rr;
          const float v = acc[i][j][rr] + bc;
          const size_t idx = (size_t)row * N + col;
          if (MODE == 0) {
            ((u16*)outp)[idx] = f2b(v);
          } else if (MODE == 1) {
            ((float*)outp)[idx] = v + res[idx];
          } else {
            const float z = 1.5957691216f * v * (1.f + 0.044715f * v * v);
            const float g = v / (1.f + __expf(-z));
            ((u16*)outp)[idx] = f2b(g);
          }
        }
      }
    }
  }
}

// ------------- GEMM (skinny, split-K in block): out f32 = A*BT^T + bias + res ----
// R3-proven version (~55 us on proj, cross-run noise +-3%). 128x128 tile,
// grid 256 blocks. 8 waves as 2M x 2N x 2K: wave tile 64x64; pair-reduce via
// LDS scratch. 4-deep 32KB stages (128KB LDS), static buffer indices, single
// barrier/iter, counted non-draining vmcnt. Requires K % 256 == 0.
// (R6's global split-K + atomicAdd REGRESSED: atomic WRITE traffic cost more
// than the occupancy gain. R1's deeper prefetch also regressed. Plateau.)
__global__ __launch_bounds__(512) void gemm_ks(const u16* __restrict__ A,
                                               const u16* __restrict__ BT,
                                               const float* __restrict__ bias,
                                               const float* __restrict__ res,
                                               float* __restrict__ outp,
                                               int M, int N, int K) {
  __shared__ __align__(16) u16 As[4][2][128 * 32];  // 64 KB
  __shared__ __align__(16) u16 Bs[4][2][128 * 32];  // 64 KB
  const int tid = threadIdx.x;
  const int wave = tid >> 6, lane = tid & 63;

  const int gx = gridDim.x, gy = gridDim.y;
  const int L = blockIdx.y * gx + blockIdx.x;
  const int xc = L & 7, wi = L >> 3;
  const int cpg = gx >> 2, rpg = gy >> 1;
  const int bxs = (xc >> 1) * cpg + (wi % cpg);
  const int bys = (xc & 1) * rpg + (wi / cpg);

  const int row0 = bys * 128, col0 = bxs * 128;
  const int kg = wave >> 2;                 // k-group: 0 = even chunks, 1 = odd
  const int wm = (wave & 1) * 64, wn = ((wave >> 1) & 1) * 64;
  const int r = lane & 15, qd = lane >> 4;

  floatx4 acc[4][4];
#pragma unroll
  for (int i = 0; i < 4; i++)
#pragma unroll
    for (int j = 0; j < 4; j++) acc[i][j] = (floatx4){0.f, 0.f, 0.f, 0.f};

  // per-thread staging: row = tid>>2, 16B slot = tid&3 (covers a 128x32 chunk)
  const int arow = tid >> 2, aslot = (tid & 3) * 8;
  const u16* Ap = A + (size_t)(row0 + arow) * K + aslot;
  const u16* Bp = BT + (size_t)(col0 + arow) * K + aslot;

  auto stage = [&](int s, int d) {   // stage s covers k = s*64 .. s*64+63
    const int k0 = s * 64;
    async16(Ap + k0, &As[d][0][tid * 8]);
    async16(Ap + k0 + 32, &As[d][1][tid * 8]);
    async16(Bp + k0, &Bs[d][0][tid * 8]);
    async16(Bp + k0 + 32, &Bs[d][1][tid * 8]);
  };
  auto compute = [&](int d) {
    bf16x8 af[4], bfr[4];
#pragma unroll
    for (int i = 0; i < 4; i++)
      af[i] = *(const bf16x8*)&As[d][kg][(wm + i * 16 + r) * 32 + qd * 8];
#pragma unroll
    for (int j = 0; j < 4; j++)
      bfr[j] = *(const bf16x8*)&Bs[d][kg][(wn + j * 16 + r) * 32 + qd * 8];
#pragma unroll
    for (int i = 0; i < 4; i++)
#pragma unroll
      for (int j = 0; j < 4; j++)
        acc[i][j] = mfma32(af[i], bfr[j], acc[i][j]);
  };

  const int nT = K >> 6;  // chunk-pairs; multiple of 4 for K in {1024, 4096}
  stage(0, 0);
  stage(1, 1);
  stage(2, 2);
  for (int tt = 0; tt < nT; tt += 4) {
#pragma unroll
    for (int d = 0; d < 4; d++) {
      const int t = tt + d;
      const int rem = nT - 1 - t;  // stages outstanding beyond t
      if (rem >= 2)
        asm volatile("s_waitcnt vmcnt(8)" ::: "memory");  // stage(t) complete
      else if (rem == 1)
        asm volatile("s_waitcnt vmcnt(4)" ::: "memory");
      else
        asm volatile("s_waitcnt vmcnt(0)" ::: "memory");
      asm volatile("s_barrier" ::: "memory");
      if (t + 3 < nT) stage(t + 3, (d + 3) & 3);
      compute(d);
    }
  }

  // ---- pair reduction (w, w+4) via LDS scratch (reuse As: 64 KB) ----
  __syncthreads();
  float* S = (float*)&As[0][0][0];
  const int p = wave & 3;
  floatx4* W = (floatx4*)S + p * 1024 + lane;
  if (kg == 1) {
#pragma unroll
    for (int i = 0; i < 4; i++)
#pragma unroll
      for (int j = 0; j < 4; j++) W[(i * 4 + j) * 64] = acc[i][j];
  }
  __syncthreads();
  if (kg == 0) {
#pragma unroll
    for (int i = 0; i < 4; i++) {
#pragma unroll
      for (int j = 0; j < 4; j++) {
        const floatx4 w2 = W[(i * 4 + j) * 64];
        const int col = col0 + wn + j * 16 + r;
        const float bc = bias[col];
#pragma unroll
        for (int rr = 0; rr < 4; rr++) {
          const int row = row0 + wm + i * 16 + qd * 4 + rr;
          const size_t idx = (size_t)row * N + col;
          outp[idx] = acc[i][j][rr] + w2[rr] + bc + res[idx];
        }
      }
    }
  }
}

// ---------------- MFMA causal flash attention, register-resident P ----------------
// 8 waves x 512 threads: wq = wave&3 picks the 32-q sub-tile (2 fragments),
// kvh = wave>>2 picks which half of the 8 ks-chunks this wave computes.
// kv-split halves per-wave work -> 2 waves/SIMD even in the long tail.
// Partial O/lsum pair-reduced once via LDS scratch at the end, then the
// R0-proven shfl normalize chain.
// Load balance: co-resident pair (L, L+256) differs only in blockIdx.z;
// qt = b ? 15-bx : bx gives every CU exactly 17 kv-iterations.
__global__ __launch_bounds__(512, 4) void attn_mfma(const u16* __restrict__ qb,
                                                    const u16* __restrict__ kb,
                                                    const u16* __restrict__ vtb,
                                                    u16* __restrict__ y) {
  const int bx = blockIdx.x;                                  // 16 q-tiles
  const int h = blockIdx.y, b = blockIdx.z;
  const int qt = b ? (15 - bx) : bx;                          // CU-complementary
  const int tid = threadIdx.x;
  const int wave = tid >> 6, lane = tid & 63;
  const int quad = lane >> 4, r = lane & 15;
  const int wq = wave & 3;    // q sub-tile (32 rows)
  const int kvh = wave >> 2;  // ks half: chunks [kvh*4, kvh*4+4)

  __shared__ __align__(16) u16 lds[2 * 128 * 64 + 2 * 64 * 128];  // 64 KB
  u16* KsB = lds;                  // [2][128*64] [key][d], d-chunks XOR-swizzled
  u16* VsB = lds + 2 * 128 * 64;   // [2][64*128] [d][key], key-chunks XOR-swizzled

  const float C = 0.125f * 1.44269504f;  // softmax scale folded into exp2, into Q
  const int qbase = qt * 128 + wq * 32;

  // Q fragments as B-operand (n=q=lane&15, k=d=quad*8+j), pre-scaled by C
  bf16x8 qf[2][2];
#pragma unroll
  for (int f = 0; f < 2; f++) {
    const u16* qp = qb + ((size_t)b * TT + qbase + f * 16 + r) * E + h * 64;
#pragma unroll
    for (int kh = 0; kh < 2; kh++) {
      union { bf16x8 v; u16 u[8]; } tmp;
#pragma unroll
      for (int j = 0; j < 8; j++) tmp.u[j] = f2b(b2f(qp[kh * 32 + quad * 8 + j]) * C);
      qf[f][kh] = tmp.v;
    }
  }

  floatx4 o[2][4];
#pragma unroll
  for (int f = 0; f < 2; f++)
#pragma unroll
    for (int i = 0; i < 4; i++) o[f][i] = (floatx4){0.f, 0.f, 0.f, 0.f};
  float lsum[2] = {0.f, 0.f};
  const bool mgt[4] = {(quad * 4 + 0) > r, (quad * 4 + 1) > r,
                       (quad * 4 + 2) > r, (quad * 4 + 3) > r};

  auto stageKV = [&](int it, int bi) {
    const int k0 = it * 128;
    u16* Kd = KsB + bi * (128 * 64);
    u16* Vd = VsB + bi * (64 * 128);
#pragma unroll
    for (int i = 0; i < 2; i++) {
      const int c = tid + i * 512;
      const int key = c >> 3, dc = (c & 7) ^ (key & 7);
      async16(kb + ((size_t)b * TT + k0 + key) * E + h * 64 + dc * 8, Kd + c * 8);
    }
#pragma unroll
    for (int i = 0; i < 2; i++) {
      const int c = tid + i * 512;
      const int d = c >> 4, kc = (c & 15) ^ (d & 15);
      async16(vtb + (size_t)(h * 64 + d) * (NB * TT) + b * TT + k0 + kc * 8,
              Vd + c * 8);
    }
  };

  const int nIter = qt + 1;
  stageKV(0, 0);
  for (int it = 0; it < nIter; it++) {
    if (it + 1 < nIter) {
      stageKV(it + 1, (it + 1) & 1);
      asm volatile("s_waitcnt vmcnt(4)" ::: "memory");
    } else {
      asm volatile("s_waitcnt vmcnt(0)" ::: "memory");
    }
    asm volatile("s_barrier" ::: "memory");
    const u16* Kb = KsB + (it & 1) * (128 * 64);
    const u16* Vb = VsB + (it & 1) * (64 * 128);
    const int k0 = it * 128;
    const int relA = (qbase - k0) >> 4;  // frag-0 straddle chunk (>=8 on full tiles)
    const int kTop = (relA + 1 < 7) ? (relA + 1) : 7;

#pragma unroll
    for (int kk = 0; kk < 4; kk++) {
      const int ks = kvh * 4 + kk;
      if (ks <= kTop) {
        // ---- S^T = K Q^T for this 16-key chunk, both q-fragments ----
        const int key = ks * 16 + r, kx = key & 7;
        const bf16x8 kf0 = *(const bf16x8*)&Kb[key * 64 + (quad ^ kx) * 8];
        const bf16x8 kf1 = *(const bf16x8*)&Kb[key * 64 + ((4 + quad) ^ kx) * 8];
        floatx4 s0 = (floatx4){0.f, 0.f, 0.f, 0.f};
        s0 = mfma32(kf0, qf[0][0], s0);
        s0 = mfma32(kf1, qf[0][1], s0);
        floatx4 s1 = (floatx4){0.f, 0.f, 0.f, 0.f};
        s1 = mfma32(kf0, qf[1][0], s1);
        s1 = mfma32(kf1, qf[1][1], s1);

        // ---- V fragments for this chunk ----
        s16x4 vf[4];
#pragma unroll
        for (int dsub = 0; dsub < 4; dsub++) {
          const int d = dsub * 16 + r;
          vf[dsub] = *(const s16x4*)&Vb[d * 128 + ((2 * ks + (quad >> 1)) ^ r) * 8 +
                                        (quad & 1) * 4];
        }

        // ---- P = exp2(S); O += P V; lsum += P ----
#pragma unroll
        for (int f = 0; f < 2; f++) {
          const floatx4 sv = (f == 0) ? s0 : s1;
          const int rel = relA + f;
          if (ks <= rel) {
            float p0 = exp2f(sv[0]);
            float p1 = exp2f(sv[1]);
            float p2 = exp2f(sv[2]);
            float p3 = exp2f(sv[3]);
            if (ks == rel) {  // diagonal straddle: lane-constant causal mask
              if (mgt[0]) p0 = 0.f;
              if (mgt[1]) p1 = 0.f;
              if (mgt[2]) p2 = 0.f;
              if (mgt[3]) p3 = 0.f;
            }
            lsum[f] += p0 + p1 + p2 + p3;
            s16x4 pk;
            pk[0] = (short)f2b_fast(p0);
            pk[1] = (short)f2b_fast(p1);
            pk[2] = (short)f2b_fast(p2);
            pk[3] = (short)f2b_fast(p3);
#pragma unroll
            for (int dsub = 0; dsub < 4; dsub++)
              o[f][dsub] = mfma16(pk, vf[dsub], o[f][dsub]);
          }
        }
      }
    }
    asm volatile("s_barrier" ::: "memory");
  }

  // ---- epilogue: pair (wq: kvh=0/1) reduction via LDS scratch, then the
  // R0-proven shfl normalize chain (lv@lane = rowsum for q = r per wave).
  floatx4* W = (floatx4*)(float*)lds + wq * 576 + lane;  // 9 slots/pair, 36 KB
  if (kvh == 1) {
#pragma unroll
    for (int f = 0; f < 2; f++)
#pragma unroll
      for (int dsub = 0; dsub < 4; dsub++) W[(f * 4 + dsub) * 64] = o[f][dsub];
    W[8 * 64] = (floatx4){lsum[0], lsum[1], 0.f, 0.f};
  }
  __syncthreads();
  if (kvh == 0) {
    const floatx4 ls2 = W[8 * 64];
#pragma unroll
    for (int f = 0; f < 2; f++) {
      float lv = lsum[f] + ((f == 0) ? ls2[0] : ls2[1]);
      lv += __shfl_xor(lv, 16);
      lv += __shfl_xor(lv, 32);  // lv@lane = total row-sum for q = qbase+f*16+(lane&15)
      float linv[4];
#pragma unroll
      for (int rr = 0; rr < 4; rr++) linv[rr] = 1.f / __shfl(lv, quad * 4 + rr);
#pragma unroll
      for (int dsub = 0; dsub < 4; dsub++) {
        const floatx4 o2 = W[(f * 4 + dsub) * 64];
#pragma unroll
        for (int rr = 0; rr < 4; rr++) {
          const size_t row = (size_t)b * TT + qbase + f * 16 + quad * 4 + rr;
          y[row * E + h * 64 + dsub * 16 + r] =
              f2b((o[f][dsub][rr] + o2[rr]) * linv[rr]);
        }
      }
    }
  }
}

extern "C" void kernel_launch(void* const* d_in, const int* in_sizes, int n_in,
                              void* d_out, int out_size, void* d_ws, size_t ws_size,
                              hipStream_t stream) {
  (void)in_sizes; (void)n_in; (void)out_size; (void)ws_size;
  const float* x      = (const float*)d_in[0];
  const float* ln1w   = (const float*)d_in[1];
  const float* ln1b   = (const float*)d_in[2];
  const float* w_qkv  = (const float*)d_in[3];
  const float* b_qkv  = (const float*)d_in[4];
  const float* w_o    = (const float*)d_in[5];
  const float* b_o    = (const float*)d_in[6];
  const float* ln2w   = (const float*)d_in[7];
  const float* ln2b   = (const float*)d_in[8];
  const float* w_fc   = (const float*)d_in[9];
  const float* b_fc   = (const float*)d_in[10];
  const float* w_proj = (const float*)d_in[11];
  const float* b_proj = (const float*)d_in[12];
  float* out = (float*)d_out;

  char* p = (char*)d_ws;
  u16* wT_qkv  = (u16*)p; p += (size_t)3072 * 1024 * 2;
  u16* wT_o    = (u16*)p; p += (size_t)1024 * 1024 * 2;
  u16* wT_fc   = (u16*)p; p += (size_t)4096 * 1024 * 2;
  u16* wT_proj = (u16*)p; p += (size_t)1024 * 4096 * 2;
  u16* hbuf    = (u16*)p; p += (size_t)4096 * 1024 * 2;   // h -> y -> h2 (serial reuse)
  u16* qkvb    = (u16*)p; p += (size_t)4096 * 3072 * 2;   // qb | kb | vtb
  float* x2    = (float*)p; p += (size_t)4096 * 1024 * 4;
  u16* gbuf    = (u16*)p; p += (size_t)4096 * 4096 * 2;

  u16* qb  = qkvb;
  u16* kb  = qkvb + (size_t)4096 * 1024;
  u16* vtb = qkvb + (size_t)8 * 1024 * 1024;

  // all four weight transposes in one launch
  wconv_all<<<12288, dim3(32, 8), 0, stream>>>(w_qkv, w_o, w_fc, w_proj,
                                               wT_qkv, wT_o, wT_fc, wT_proj);

  // h = LN1(x)
  ln_kernel<<<4096, 256, 0, stream>>>(x, ln1w, ln1b, hbuf);
  // qkv = h @ w_qkv + b_qkv  (split: qb, kb row-major; vtb transposed)
  gemm_bt<3, 256><<<dim3(3072 / 128, 4096 / 256), 512, 0, stream>>>(
      hbuf, wT_qkv, b_qkv, nullptr, qkvb, 4096, 3072, 1024);
  // y = attention(q,k,v)   (writes into hbuf, h is dead)
  attn_mfma<<<dim3(16, NH, NB), 512, 0, stream>>>(qb, kb, vtb, hbuf);
  // x2 = x + y @ w_o + b_o   (split-K skinny GEMM)
  gemm_ks<<<dim3(1024 / 128, 4096 / 128), 512, 0, stream>>>(
      hbuf, wT_o, b_o, x, x2, 4096, 1024, 1024);
  // h2 = LN2(x2)  (into hbuf, y is dead)
  ln_kernel<<<4096, 256, 0, stream>>>(x2, ln2w, ln2b, hbuf);
  // g = gelu(h2 @ w_fc + b_fc)
  gemm_bt<2, 256><<<dim3(4096 / 128, 4096 / 256), 512, 0, stream>>>(
      hbuf, wT_fc, b_fc, nullptr, gbuf, 4096, 4096, 1024);
  // out = x2 + g @ w_proj + b_proj   (split-K skinny GEMM)
  gemm_ks<<<dim3(1024 / 128, 4096 / 128), 512, 0, stream>>>(
      gbuf, wT_proj, b_proj, x2, out, 4096, 1024, 4096);
}

// Round 11
// 310.090 us; speedup vs baseline: 1.0615x; 1.0391x over previous
//
#include <hip/hip_runtime.h>
#include <cstdint>
#include <cstddef>

#define E 1024
#define TT 2048
#define NB 2
#define NH 16
#define HD 64

using u16 = unsigned short;
using bf16x8 = __attribute__((ext_vector_type(8))) __bf16;
using floatx4 = __attribute__((ext_vector_type(4))) float;
using s16x4 = __attribute__((ext_vector_type(4))) short;

__device__ __forceinline__ float b2f(u16 u) {
  unsigned int x = ((unsigned int)u) << 16;
  float f;
  __builtin_memcpy(&f, &x, 4);
  return f;
}
__device__ __forceinline__ u16 f2b(float f) {
  unsigned int x;
  __builtin_memcpy(&x, &f, 4);
  x += 0x7fffu + ((x >> 16) & 1u);
  return (u16)(x >> 16);
}
__device__ __forceinline__ u16 f2b_fast(float f) {  // compensated truncation
  unsigned int x;
  float g = f * 1.001953125f;
  __builtin_memcpy(&x, &g, 4);
  return (u16)(x >> 16);
}

__device__ __forceinline__ void async16(const u16* g, u16* l) {
  __builtin_amdgcn_global_load_lds(
      (const __attribute__((address_space(1))) unsigned int*)g,
      (__attribute__((address_space(3))) unsigned int*)l, 16, 0, 0);
}

__device__ __forceinline__ floatx4 mfma32(bf16x8 a, bf16x8 b, floatx4 c) {
  return __builtin_amdgcn_mfma_f32_16x16x32_bf16(a, b, c, 0, 0, 0);
}

// v_mfma_f32_16x16x16_bf16 (A/B = 4 bf16 in 2 VGPRs). Builtin only exists on
// the device target; host pass parses this body too, so guard it.
__device__ __forceinline__ floatx4 mfma16(s16x4 a, s16x4 b, floatx4 c) {
#if defined(__HIP_DEVICE_COMPILE__)
  return __builtin_amdgcn_mfma_f32_16x16x16bf16_1k(a, b, c, 0, 0, 0);
#else
  return c;
#endif
}

// ---------------- merged weight convert fp32[K][N] -> bf16[N][K] ----------------
// Stores vectorized: one ushort4 (8B) per thread (G13 applies to stores too).
__global__ __launch_bounds__(256) void wconv_all(
    const float* __restrict__ w0, const float* __restrict__ w1,
    const float* __restrict__ w2, const float* __restrict__ w3,
    u16* __restrict__ o0, u16* __restrict__ o1, u16* __restrict__ o2,
    u16* __restrict__ o3) {
  __shared__ float tile[32][33];
  const int t = blockIdx.x;
  const float* w;
  u16* o;
  int K, N, nx, ti;
  if (t < 3072) { w = w0; o = o0; K = 1024; N = 3072; nx = 96; ti = t; }
  else if (t < 4096) { w = w1; o = o1; K = 1024; N = 1024; nx = 32; ti = t - 3072; }
  else if (t < 8192) { w = w2; o = o2; K = 1024; N = 4096; nx = 128; ti = t - 4096; }
  else { w = w3; o = o3; K = 4096; N = 1024; nx = 32; ti = t - 8192; }
  const int n0 = (ti % nx) * 32, k0 = (ti / nx) * 32;
  const int tx = threadIdx.x, ty = threadIdx.y;
#pragma unroll
  for (int i = 0; i < 32; i += 8)
    tile[ty + i][tx] = w[(size_t)(k0 + ty + i) * N + (n0 + tx)];
  __syncthreads();
  const int ft = ty * 32 + tx;          // 0..255
  const int nl = ft >> 3, ch = ft & 7;  // out row (n), 4-wide k-chunk
  ushort4 pk;
  pk.x = f2b(tile[ch * 4 + 0][nl]);
  pk.y = f2b(tile[ch * 4 + 1][nl]);
  pk.z = f2b(tile[ch * 4 + 2][nl]);
  pk.w = f2b(tile[ch * 4 + 3][nl]);
  *(ushort4*)(o + (size_t)(n0 + nl) * K + k0 + ch * 4) = pk;
}

// ---------------- LayerNorm fp32 in -> bf16 out ----------------
__global__ __launch_bounds__(256) void ln_kernel(const float* __restrict__ x,
                                                 const float* __restrict__ w,
                                                 const float* __restrict__ bvec,
                                                 u16* __restrict__ outb) {
  const int row = blockIdx.x;
  const int t = threadIdx.x;
  const float4 v = ((const float4*)(x + (size_t)row * E))[t];
  float s1 = v.x + v.y + v.z + v.w;
  float s2 = v.x * v.x + v.y * v.y + v.z * v.z + v.w * v.w;
#pragma unroll
  for (int off = 32; off > 0; off >>= 1) {
    s1 += __shfl_down(s1, off);
    s2 += __shfl_down(s2, off);
  }
  __shared__ float r1[4], r2[4];
  if ((t & 63) == 0) { r1[t >> 6] = s1; r2[t >> 6] = s2; }
  __syncthreads();
  s1 = r1[0] + r1[1] + r1[2] + r1[3];
  s2 = r2[0] + r2[1] + r2[2] + r2[3];
  const float mean = s1 * (1.f / E);
  const float var = s2 * (1.f / E) - mean * mean;
  const float rstd = rsqrtf(var + 1e-5f);
  const float4 wv = ((const float4*)w)[t];
  const float4 bv = ((const float4*)bvec)[t];
  const u16 o0 = f2b((v.x - mean) * rstd * wv.x + bv.x);
  const u16 o1 = f2b((v.y - mean) * rstd * wv.y + bv.y);
  const u16 o2 = f2b((v.z - mean) * rstd * wv.z + bv.z);
  const u16 o3 = f2b((v.w - mean) * rstd * wv.w + bv.w);
  uint2 pk;
  pk.x = (unsigned)o0 | ((unsigned)o1 << 16);
  pk.y = (unsigned)o2 | ((unsigned)o3 << 16);
  ((uint2*)(outb + (size_t)row * E))[t] = pk;
}

// ---------------- GEMM (fat): C[M][N] = A[M][K](bf16) * BT[N][K](bf16)^T --------
// R7-proven version (best measured total 317.1 us): 512 threads, 256x128 tile,
// wave 64x64, DEPTH=3 buffers (72KB LDS -> 2 blocks/CU), ONE barrier/iter,
// counted non-draining vmcnt(3). (R8's 256x256 tile REGRESSED +12us: 1 block/CU
// loses inter-block latency hiding; big tiles need the 8-phase schedule.)
template <int MODE, int ROWS>
__global__ __launch_bounds__(512) void gemm_bt(const u16* __restrict__ A,
                                               const u16* __restrict__ BT,
                                               const float* __restrict__ bias,
                                               const float* __restrict__ res,
                                               void* __restrict__ outp,
                                               int M, int N, int K) {
  constexpr int NJ = (ROWS == 256) ? 4 : 2;
  __shared__ __align__(16) u16 As[3][ROWS * 32];
  __shared__ __align__(16) u16 Bs[3][128 * 32];
  const int tid = threadIdx.x;
  const int wave = tid >> 6, lane = tid & 63;

  // XCD-aware rasterization (dispatch round-robins blocks over 8 XCDs).
  const int gx = gridDim.x, gy = gridDim.y;
  const int L = blockIdx.y * gx + blockIdx.x;
  const int xc = L & 7, wi = L >> 3;
  const int cpg = gx >> 2;
  const int rpg = gy >> 1;
  const int bxs = (xc >> 1) * cpg + (wi % cpg);
  const int bys = (xc & 1) * rpg + (wi / cpg);

  const int row0 = bys * ROWS, col0 = bxs * 128;
  const int wm = (ROWS == 256) ? (wave & 3) * 64 : (wave & 1) * 64;
  const int wn = (ROWS == 256) ? (wave >> 2) * 64 : (wave >> 1) * 32;
  const int r = lane & 15, qd = lane >> 4;

  floatx4 acc[4][NJ];
#pragma unroll
  for (int i = 0; i < 4; i++)
#pragma unroll
    for (int j = 0; j < NJ; j++) acc[i][j] = (floatx4){0.f, 0.f, 0.f, 0.f};

  // staging chunk assignments (16 B chunks; A: ROWS*4 chunks, B: 512 chunks)
  const int cA0 = tid, cA1 = tid + 512, cB = tid;
  const u16* ApA = A + (size_t)(row0 + (cA0 >> 2)) * K + (cA0 & 3) * 8;
  const u16* ApB = A + (size_t)(row0 + (cA1 >> 2)) * K + (cA1 & 3) * 8;
  const u16* Bp = BT + (size_t)(col0 + (cB >> 2)) * K + (cB & 3) * 8;

  auto stage = [&](int kt, u16* Asb, u16* Bsb) {
    async16(ApA + kt, Asb + cA0 * 8);
    if (ROWS == 256) async16(ApB + kt, Asb + cA1 * 8);
    async16(Bp + kt, Bsb + cB * 8);
  };
  auto compute = [&](const u16* Asb, const u16* Bsb) {
    bf16x8 af[4], bfr[NJ];
#pragma unroll
    for (int i = 0; i < 4; i++)
      af[i] = *(const bf16x8*)&Asb[(wm + i * 16 + r) * 32 + qd * 8];
#pragma unroll
    for (int j = 0; j < NJ; j++)
      bfr[j] = *(const bf16x8*)&Bsb[(wn + j * 16 + r) * 32 + qd * 8];
#pragma unroll
    for (int i = 0; i < 4; i++)
#pragma unroll
      for (int j = 0; j < NJ; j++)
        acc[i][j] = mfma32(af[i], bfr[j], acc[i][j]);
  };

  const int nIter = K >> 5;
  stage(0, As[0], Bs[0]);
  stage(32, As[1], Bs[1]);
  for (int tt = 0; tt < nIter; tt += 3) {
#pragma unroll
    for (int d = 0; d < 3; d++) {
      const int t = tt + d;
      if (t >= nIter) break;  // uniform across block
      if (t + 1 < nIter) {
        if (ROWS == 256)
          asm volatile("s_waitcnt vmcnt(3)" ::: "memory");  // stage(t) complete
        else
          asm volatile("s_waitcnt vmcnt(2)" ::: "memory");
      } else {
        asm volatile("s_waitcnt vmcnt(0)" ::: "memory");
      }
      asm volatile("s_barrier" ::: "memory");
      if (t + 2 < nIter) {
        const int sd = (d + 2 >= 3) ? d - 1 : d + 2;  // (d+2)%3, static
        stage((t + 2) * 32, As[sd], Bs[sd]);
      }
      compute(As[d], Bs[d]);
    }
  }

#pragma unroll
  for (int i = 0; i < 4; i++) {
#pragma unroll
    for (int j = 0; j < NJ; j++) {
      const int col = col0 + wn + j * 16 + r;
      const float bc = bias[col];
      if (MODE == 3) {
        u16* base = (u16*)outp;
        const int rowb = row0 + wm + i * 16 + qd * 4;
        if (col < 2048) {
          const size_t cb =
              (col < 1024) ? (size_t)col : ((size_t)4096 * 1024 + (col - 1024));
#pragma unroll
          for (int rr = 0; rr < 4; rr++)
            base[cb + (size_t)(rowb + rr) * 1024] = f2b(acc[i][j][rr] + bc);
        } else {
          ushort4 pk;
          pk.x = f2b(acc[i][j][0] + bc);
          pk.y = f2b(acc[i][j][1] + bc);
          pk.z = f2b(acc[i][j][2] + bc);
          pk.w = f2b(acc[i][j][3] + bc);
          *(ushort4*)(base + (size_t)8 * 1024 * 1024 +
                      (size_t)(col - 2048) * 4096 + rowb) = pk;
        }
      } else {
#pragma unroll
        for (int rr = 0; rr < 4; rr++) {
          const int row = row0 + wm + i * 16 + qd * 4 + rr;
          const float v = acc[i][j][rr] + bc;
          const size_t idx = (size_t)row * N + col;
          if (MODE == 0) {
            ((u16*)outp)[idx] = f2b(v);
          } else if (MODE == 1) {
            ((float*)outp)[idx] = v + res[idx];
          } else {
            const float z = 1.5957691216f * v * (1.f + 0.044715f * v * v);
            const float g = v / (1.f + __expf(-z));
            ((u16*)outp)[idx] = f2b(g);
          }
        }
      }
    }
  }
}

// ------- GEMM (skinny, split-M): out f32 = A*BT^T + bias + res -------
// 64x128 tile -> grid (N/128, M/64) = 512 blocks = 2 blocks/CU (72KB LDS),
// 4 waves/SIMD mutual latency hiding with PLAIN stores (no atomics -- R6's
// split-K atomic traffic regressed; this gets the same occupancy for free).
// 8 waves as 2M x 2N x 2K, wave tile 32x64; kg pair-reduce via LDS scratch.
// LDS row-major [rows][64] (linear global_load_lds dest); stride-128B rows
// would be a 16-way read conflict -> XOR-swizzle k-chunk by (row&7) on BOTH
// the global source and the ds_read (rule #21; same pattern as attn Ks).
// DEPTH=3, one barrier/iter, counted non-draining vmcnt(3) (3 loads/stage).
// Requires K % 64 == 0, nT >= 2: K=1024, 4096 ok.
__global__ __launch_bounds__(512, 4) void gemm_ks(const u16* __restrict__ A,
                                                  const u16* __restrict__ BT,
                                                  const float* __restrict__ bias,
                                                  const float* __restrict__ res,
                                                  float* __restrict__ outp,
                                                  int M, int N, int K) {
  __shared__ __align__(16) u16 lds[3 * (64 * 64 + 128 * 64)];  // 72 KB
  u16* AsB = lds;                       // 3 x [64][64]
  u16* BsB = lds + 3 * 64 * 64;         // 3 x [128][64]
  const int tid = threadIdx.x;
  const int wave = tid >> 6, lane = tid & 63;

  const int gx = gridDim.x, gy = gridDim.y;
  const int L = blockIdx.y * gx + blockIdx.x;
  const int xc = L & 7, wi = L >> 3;
  const int cpg = gx >> 2, rpg = gy >> 1;
  const int bxs = (xc >> 1) * cpg + (wi % cpg);
  const int bys = (xc & 1) * rpg + (wi / cpg);

  const int row0 = bys * 64, col0 = bxs * 128;
  const int kg = wave >> 2;                 // k-group: lower/upper 32 of stage
  const int wm = (wave & 1) * 32, wn = ((wave >> 1) & 1) * 64;
  const int r = lane & 15, qd = lane >> 4;

  floatx4 acc[2][4];
#pragma unroll
  for (int i = 0; i < 2; i++)
#pragma unroll
    for (int j = 0; j < 4; j++) acc[i][j] = (floatx4){0.f, 0.f, 0.f, 0.f};

  // staging: linear LDS dest (chunk = tid, tid, 512+tid); global k-chunk
  // pre-swizzled by (row&7) so the row-major tile is read conflict-free.
  const int arow = tid >> 3;                       // A row 0..63 (also B row low)
  const int aks = (tid & 7) ^ (arow & 7);          // swizzled k-chunk
  const u16* Ap = A + (size_t)(row0 + arow) * K + aks * 8;
  const u16* Bp1 = BT + (size_t)(col0 + arow) * K + aks * 8;          // rows 0..63
  const u16* Bp2 = BT + (size_t)(col0 + 64 + arow) * K + aks * 8;     // rows 64..127

  auto stage = [&](int s, int d) {   // stage s covers k = s*64 .. s*64+63
    const int k0 = s * 64;
    async16(Ap + k0, AsB + d * (64 * 64) + tid * 8);
    async16(Bp1 + k0, BsB + d * (128 * 64) + tid * 8);
    async16(Bp2 + k0, BsB + d * (128 * 64) + (512 + tid) * 8);
  };
  auto compute = [&](int d) {
    const u16* Ad = AsB + d * (64 * 64);
    const u16* Bd = BsB + d * (128 * 64);
    const int c = kg * 4 + qd;  // k-chunk within stage (8 elems each)
    bf16x8 af[2], bfr[4];
#pragma unroll
    for (int i = 0; i < 2; i++) {
      const int row = wm + i * 16 + r;
      af[i] = *(const bf16x8*)&Ad[row * 64 + (c ^ (row & 7)) * 8];
    }
#pragma unroll
    for (int j = 0; j < 4; j++) {
      const int row = wn + j * 16 + r;
      bfr[j] = *(const bf16x8*)&Bd[row * 64 + (c ^ (row & 7)) * 8];
    }
#pragma unroll
    for (int i = 0; i < 2; i++)
#pragma unroll
      for (int j = 0; j < 4; j++)
        acc[i][j] = mfma32(af[i], bfr[j], acc[i][j]);
  };

  const int nT = K >> 6;  // 16 (w_o) / 64 (proj)
  stage(0, 0);
  stage(1, 1);
  for (int tt = 0; tt < nT; tt += 3) {
#pragma unroll
    for (int d = 0; d < 3; d++) {
      const int t = tt + d;
      if (t >= nT) break;  // uniform across block
      if (t + 1 < nT)
        asm volatile("s_waitcnt vmcnt(3)" ::: "memory");  // stage(t) complete
      else
        asm volatile("s_waitcnt vmcnt(0)" ::: "memory");
      asm volatile("s_barrier" ::: "memory");
      if (t + 2 < nT) {
        const int sd = (d + 2 >= 3) ? d - 1 : d + 2;  // (d+2)%3, static
        stage(t + 2, sd);
      }
      compute(d);
    }
  }

  // ---- pair reduction (wave, wave+4) via LDS scratch (32 KB of 72) ----
  __syncthreads();
  floatx4* W = (floatx4*)lds + (wave & 3) * 512 + lane;  // 8 slots x 64 lanes/pair
  if (kg == 1) {
#pragma unroll
    for (int i = 0; i < 2; i++)
#pragma unroll
      for (int j = 0; j < 4; j++) W[(i * 4 + j) * 64] = acc[i][j];
  }
  __syncthreads();
  if (kg == 0) {
#pragma unroll
    for (int i = 0; i < 2; i++) {
#pragma unroll
      for (int j = 0; j < 4; j++) {
        const floatx4 w2 = W[(i * 4 + j) * 64];
        const int col = col0 + wn + j * 16 + r;
        const float bc = bias[col];
#pragma unroll
        for (int rr = 0; rr < 4; rr++) {
          const int row = row0 + wm + i * 16 + qd * 4 + rr;
          const size_t idx = (size_t)row * N + col;
          outp[idx] = acc[i][j][rr] + w2[rr] + bc + res[idx];
        }
      }
    }
  }
}

// ---------------- MFMA causal flash attention, register-resident P ----------------
// 8 waves x 512 threads: wq = wave&3 picks the 32-q sub-tile (2 fragments),
// kvh = wave>>2 picks which half of the 8 ks-chunks this wave computes.
// kv-split halves per-wave work -> 2 waves/SIMD even in the long tail.
// Partial O/lsum pair-reduced once via LDS scratch at the end, then the
// R0-proven shfl normalize chain.
// Load balance: co-resident pair (L, L+256) differs only in blockIdx.z;
// qt = b ? 15-bx : bx gives every CU exactly 17 kv-iterations.
__global__ __launch_bounds__(512, 4) void attn_mfma(const u16* __restrict__ qb,
                                                    const u16* __restrict__ kb,
                                                    const u16* __restrict__ vtb,
                                                    u16* __restrict__ y) {
  const int bx = blockIdx.x;                                  // 16 q-tiles
  const int h = blockIdx.y, b = blockIdx.z;
  const int qt = b ? (15 - bx) : bx;                          // CU-complementary
  const int tid = threadIdx.x;
  const int wave = tid >> 6, lane = tid & 63;
  const int quad = lane >> 4, r = lane & 15;
  const int wq = wave & 3;    // q sub-tile (32 rows)
  const int kvh = wave >> 2;  // ks half: chunks [kvh*4, kvh*4+4)

  __shared__ __align__(16) u16 lds[2 * 128 * 64 + 2 * 64 * 128];  // 64 KB
  u16* KsB = lds;                  // [2][128*64] [key][d], d-chunks XOR-swizzled
  u16* VsB = lds + 2 * 128 * 64;   // [2][64*128] [d][key], key-chunks XOR-swizzled

  const float C = 0.125f * 1.44269504f;  // softmax scale folded into exp2, into Q
  const int qbase = qt * 128 + wq * 32;

  // Q fragments as B-operand (n=q=lane&15, k=d=quad*8+j), pre-scaled by C
  bf16x8 qf[2][2];
#pragma unroll
  for (int f = 0; f < 2; f++) {
    const u16* qp = qb + ((size_t)b * TT + qbase + f * 16 + r) * E + h * 64;
#pragma unroll
    for (int kh = 0; kh < 2; kh++) {
      union { bf16x8 v; u16 u[8]; } tmp;
#pragma unroll
      for (int j = 0; j < 8; j++) tmp.u[j] = f2b(b2f(qp[kh * 32 + quad * 8 + j]) * C);
      qf[f][kh] = tmp.v;
    }
  }

  floatx4 o[2][4];
#pragma unroll
  for (int f = 0; f < 2; f++)
#pragma unroll
    for (int i = 0; i < 4; i++) o[f][i] = (floatx4){0.f, 0.f, 0.f, 0.f};
  float lsum[2] = {0.f, 0.f};
  const bool mgt[4] = {(quad * 4 + 0) > r, (quad * 4 + 1) > r,
                       (quad * 4 + 2) > r, (quad * 4 + 3) > r};

  auto stageKV = [&](int it, int bi) {
    const int k0 = it * 128;
    u16* Kd = KsB + bi * (128 * 64);
    u16* Vd = VsB + bi * (64 * 128);
#pragma unroll
    for (int i = 0; i < 2; i++) {
      const int c = tid + i * 512;
      const int key = c >> 3, dc = (c & 7) ^ (key & 7);
      async16(kb + ((size_t)b * TT + k0 + key) * E + h * 64 + dc * 8, Kd + c * 8);
    }
#pragma unroll
    for (int i = 0; i < 2; i++) {
      const int c = tid + i * 512;
      const int d = c >> 4, kc = (c & 15) ^ (d & 15);
      async16(vtb + (size_t)(h * 64 + d) * (NB * TT) + b * TT + k0 + kc * 8,
              Vd + c * 8);
    }
  };

  const int nIter = qt + 1;
  stageKV(0, 0);
  for (int it = 0; it < nIter; it++) {
    if (it + 1 < nIter) {
      stageKV(it + 1, (it + 1) & 1);
      asm volatile("s_waitcnt vmcnt(4)" ::: "memory");
    } else {
      asm volatile("s_waitcnt vmcnt(0)" ::: "memory");
    }
    asm volatile("s_barrier" ::: "memory");
    const u16* Kb = KsB + (it & 1) * (128 * 64);
    const u16* Vb = VsB + (it & 1) * (64 * 128);
    const int k0 = it * 128;
    const int relA = (qbase - k0) >> 4;  // frag-0 straddle chunk (>=8 on full tiles)
    const int kTop = (relA + 1 < 7) ? (relA + 1) : 7;

#pragma unroll
    for (int kk = 0; kk < 4; kk++) {
      const int ks = kvh * 4 + kk;
      if (ks <= kTop) {
        // ---- S^T = K Q^T for this 16-key chunk, both q-fragments ----
        const int key = ks * 16 + r, kx = key & 7;
        const bf16x8 kf0 = *(const bf16x8*)&Kb[key * 64 + (quad ^ kx) * 8];
        const bf16x8 kf1 = *(const bf16x8*)&Kb[key * 64 + ((4 + quad) ^ kx) * 8];
        floatx4 s0 = (floatx4){0.f, 0.f, 0.f, 0.f};
        s0 = mfma32(kf0, qf[0][0], s0);
        s0 = mfma32(kf1, qf[0][1], s0);
        floatx4 s1 = (floatx4){0.f, 0.f, 0.f, 0.f};
        s1 = mfma32(kf0, qf[1][0], s1);
        s1 = mfma32(kf1, qf[1][1], s1);

        // ---- V fragments for this chunk ----
        s16x4 vf[4];
#pragma unroll
        for (int dsub = 0; dsub < 4; dsub++) {
          const int d = dsub * 16 + r;
          vf[dsub] = *(const s16x4*)&Vb[d * 128 + ((2 * ks + (quad >> 1)) ^ r) * 8 +
                                        (quad & 1) * 4];
        }

        // ---- P = exp2(S); O += P V; lsum += P ----
#pragma unroll
        for (int f = 0; f < 2; f++) {
          const floatx4 sv = (f == 0) ? s0 : s1;
          const int rel = relA + f;
          if (ks <= rel) {
            float p0 = exp2f(sv[0]);
            float p1 = exp2f(sv[1]);
            float p2 = exp2f(sv[2]);
            float p3 = exp2f(sv[3]);
            if (ks == rel) {  // diagonal straddle: lane-constant causal mask
              if (mgt[0]) p0 = 0.f;
              if (mgt[1]) p1 = 0.f;
              if (mgt[2]) p2 = 0.f;
              if (mgt[3]) p3 = 0.f;
            }
            lsum[f] += p0 + p1 + p2 + p3;
            s16x4 pk;
            pk[0] = (short)f2b_fast(p0);
            pk[1] = (short)f2b_fast(p1);
            pk[2] = (short)f2b_fast(p2);
            pk[3] = (short)f2b_fast(p3);
#pragma unroll
            for (int dsub = 0; dsub < 4; dsub++)
              o[f][dsub] = mfma16(pk, vf[dsub], o[f][dsub]);
          }
        }
      }
    }
    asm volatile("s_barrier" ::: "memory");
  }

  // ---- epilogue: pair (wq: kvh=0/1) reduction via LDS scratch, then the
  // R0-proven shfl normalize chain (lv@lane = rowsum for q = r per wave).
  floatx4* W = (floatx4*)(float*)lds + wq * 576 + lane;  // 9 slots/pair, 36 KB
  if (kvh == 1) {
#pragma unroll
    for (int f = 0; f < 2; f++)
#pragma unroll
      for (int dsub = 0; dsub < 4; dsub++) W[(f * 4 + dsub) * 64] = o[f][dsub];
    W[8 * 64] = (floatx4){lsum[0], lsum[1], 0.f, 0.f};
  }
  __syncthreads();
  if (kvh == 0) {
    const floatx4 ls2 = W[8 * 64];
#pragma unroll
    for (int f = 0; f < 2; f++) {
      float lv = lsum[f] + ((f == 0) ? ls2[0] : ls2[1]);
      lv += __shfl_xor(lv, 16);
      lv += __shfl_xor(lv, 32);  // lv@lane = total row-sum for q = qbase+f*16+(lane&15)
      float linv[4];
#pragma unroll
      for (int rr = 0; rr < 4; rr++) linv[rr] = 1.f / __shfl(lv, quad * 4 + rr);
#pragma unroll
      for (int dsub = 0; dsub < 4; dsub++) {
        const floatx4 o2 = W[(f * 4 + dsub) * 64];
#pragma unroll
        for (int rr = 0; rr < 4; rr++) {
          const size_t row = (size_t)b * TT + qbase + f * 16 + quad * 4 + rr;
          y[row * E + h * 64 + dsub * 16 + r] =
              f2b((o[f][dsub][rr] + o2[rr]) * linv[rr]);
        }
      }
    }
  }
}

extern "C" void kernel_launch(void* const* d_in, const int* in_sizes, int n_in,
                              void* d_out, int out_size, void* d_ws, size_t ws_size,
                              hipStream_t stream) {
  (void)in_sizes; (void)n_in; (void)out_size; (void)ws_size;
  const float* x      = (const float*)d_in[0];
  const float* ln1w   = (const float*)d_in[1];
  const float* ln1b   = (const float*)d_in[2];
  const float* w_qkv  = (const float*)d_in[3];
  const float* b_qkv  = (const float*)d_in[4];
  const float* w_o    = (const float*)d_in[5];
  const float* b_o    = (const float*)d_in[6];
  const float* ln2w   = (const float*)d_in[7];
  const float* ln2b   = (const float*)d_in[8];
  const float* w_fc   = (const float*)d_in[9];
  const float* b_fc   = (const float*)d_in[10];
  const float* w_proj = (const float*)d_in[11];
  const float* b_proj = (const float*)d_in[12];
  float* out = (float*)d_out;

  char* p = (char*)d_ws;
  u16* wT_qkv  = (u16*)p; p += (size_t)3072 * 1024 * 2;
  u16* wT_o    = (u16*)p; p += (size_t)1024 * 1024 * 2;
  u16* wT_fc   = (u16*)p; p += (size_t)4096 * 1024 * 2;
  u16* wT_proj = (u16*)p; p += (size_t)1024 * 4096 * 2;
  u16* hbuf    = (u16*)p; p += (size_t)4096 * 1024 * 2;   // h -> y -> h2 (serial reuse)
  u16* qkvb    = (u16*)p; p += (size_t)4096 * 3072 * 2;   // qb | kb | vtb
  float* x2    = (float*)p; p += (size_t)4096 * 1024 * 4;
  u16* gbuf    = (u16*)p; p += (size_t)4096 * 4096 * 2;

  u16* qb  = qkvb;
  u16* kb  = qkvb + (size_t)4096 * 1024;
  u16* vtb = qkvb + (size_t)8 * 1024 * 1024;

  // all four weight transposes in one launch
  wconv_all<<<12288, dim3(32, 8), 0, stream>>>(w_qkv, w_o, w_fc, w_proj,
                                               wT_qkv, wT_o, wT_fc, wT_proj);

  // h = LN1(x)
  ln_kernel<<<4096, 256, 0, stream>>>(x, ln1w, ln1b, hbuf);
  // qkv = h @ w_qkv + b_qkv  (split: qb, kb row-major; vtb transposed)
  gemm_bt<3, 256><<<dim3(3072 / 128, 4096 / 256), 512, 0, stream>>>(
      hbuf, wT_qkv, b_qkv, nullptr, qkvb, 4096, 3072, 1024);
  // y = attention(q,k,v)   (writes into hbuf, h is dead)
  attn_mfma<<<dim3(16, NH, NB), 512, 0, stream>>>(qb, kb, vtb, hbuf);
  // x2 = x + y @ w_o + b_o   (split-M skinny GEMM, 2 blocks/CU)
  gemm_ks<<<dim3(1024 / 128, 4096 / 64), 512, 0, stream>>>(
      hbuf, wT_o, b_o, x, x2, 4096, 1024, 1024);
  // h2 = LN2(x2)  (into hbuf, y is dead)
  ln_kernel<<<4096, 256, 0, stream>>>(x2, ln2w, ln2b, hbuf);
  // g = gelu(h2 @ w_fc + b_fc)
  gemm_bt<2, 256><<<dim3(4096 / 128, 4096 / 256), 512, 0, stream>>>(
      hbuf, wT_fc, b_fc, nullptr, gbuf, 4096, 4096, 1024);
  // out = x2 + g @ w_proj + b_proj   (split-M skinny GEMM, 2 blocks/CU)
  gemm_ks<<<dim3(1024 / 128, 4096 / 64), 512, 0, stream>>>(
      gbuf, wT_proj, b_proj, x2, out, 4096, 1024, 4096);
}